// Round 6
// baseline (443.827 us; speedup 1.0000x reference)
//
#include <hip/hip_runtime.h>
#include <hip/hip_bf16.h>
#include <math.h>

// Problem constants
#define B_   4
#define CIN  256
#define COUT 256
#define HW   4096   // 64*64

typedef __attribute__((ext_vector_type(8))) short short8;
typedef __attribute__((ext_vector_type(4))) float float4v;

// LDS row stride (ushorts). 80 B: 16B-aligned, period-8 bank pattern -> 2-way (free).
#define LSTR 40

__device__ __forceinline__ float sigmoidf_(float v){ return 1.0f/(1.0f+expf(-v)); }
__device__ __forceinline__ ushort f2bf(float f){
  union { float f; unsigned u; } x; x.f = f;
  unsigned r = x.u + 0x7fffu + ((x.u>>16)&1u);
  return (ushort)(r>>16);
}
__device__ __forceinline__ float bflo(unsigned u){ union{unsigned u; float f;} c; c.u = u<<16;          return c.f; }
__device__ __forceinline__ float bfhi(unsigned u){ union{unsigned u; float f;} c; c.u = u & 0xffff0000u; return c.f; }

// ---------- transpose x [B][C][HW] -> xtb [B][HW][C] bf16 ----------
__global__ void k_transpose_x(const float* __restrict__ x, ushort* __restrict__ xtb){
  __shared__ float ts[32][33];
  int tx = threadIdx.x & 31, ty = threadIdx.x >> 5;
  int p0 = blockIdx.x * 32, c0 = blockIdx.y * 32, b = blockIdx.z;
  const float* xb = x + (size_t)b*CIN*HW;
#pragma unroll
  for(int q=0;q<4;q++){
    int c = ty + q*8;
    ts[c][tx] = xb[(size_t)(c0+c)*HW + p0+tx];
  }
  __syncthreads();
#pragma unroll
  for(int q=0;q<4;q++){
    int pr = ty + q*8;
    xtb[((size_t)(b*HW + p0+pr)<<8) + c0+tx] = f2bf(ts[tx][pr]);
  }
}

// ---------- weight re-layouts (bf16, K-chunked [kc][o][kk]) ----------
__global__ void k_build_Wob(const float* __restrict__ w_off, ushort* __restrict__ Wob){
  int f = blockIdx.x*256 + threadIdx.x;   // grid 288
  int kc = f>>10, o = (f>>5)&31, kk = f&31;
  int k = kc*32 + kk, tap = k>>8, c = k&255;
  float v = (o < 27) ? w_off[(size_t)o*2304 + c*9 + tap] : 0.f;
  Wob[f] = f2bf(v);
}
__global__ void k_build_Wdb(const float* __restrict__ w_dcn, ushort* __restrict__ Wdb){
  int f = blockIdx.x*256 + threadIdx.x;  // grid 2304
  int kc = f>>13, o = (f>>5)&255, kk = f&31;
  int k = kc>>3, c = ((kc&7)<<5) | kk;
  Wdb[f] = f2bf(w_dcn[(size_t)o*2304 + c*9 + k]);
}
__global__ void k_build_WT2c(const float* __restrict__ w_up, ushort* __restrict__ WT2c){
  int f = blockIdx.x*256 + threadIdx.x;    // grid 4096
  int pp = f>>18, kc = (f>>13)&31, o = (f>>5)&255, kk = f&31;
  int k = kc*32 + kk, ab = k>>8, c = k&255;
  int a = ab>>1, bb = ab&1, ph = pp>>1, pw = pp&1;
  WT2c[f] = f2bf(w_up[(size_t)(c*COUT+o)*16 + (3-ph-2*a)*4 + (3-pw-2*bb)]);
}

// ---------- offset conv MFMA: M=32(27), Nb=32 px, K=2304, reg-prefetch ----------
// grid (128,4) = 512 blocks (2/CU), 256 thr = 4 waves; wave (mi,ni) owns one 16x16 tile.
__global__ __launch_bounds__(256) void k_offset_mfma(const ushort* __restrict__ xtb,
                        const ushort* __restrict__ Wob, float* __restrict__ om){
  __shared__ ushort Ws[32*LSTR];
  __shared__ ushort Vs[32*LSTR];
  __shared__ int sIdx[288];
  int tid = threadIdx.x;
  int px0 = blockIdx.x * 32;
  int b   = blockIdx.y;
  for(int t=tid; t<288; t+=256){
    int tap = t>>5, px = t&31;
    int p = px0+px, hh = p>>6, ww = p&63;
    int ih = hh + tap/3 - 1, iw = ww + tap%3 - 1;
    sIdx[t] = (ih>=0 && ih<64 && iw>=0 && iw<64) ? ((b*HW + ih*64+iw)<<8) : -1;
  }
  __syncthreads();

  int lane = tid&63, wv = tid>>6, lo = lane&15, hi = lane>>4;
  int mi = wv>>1, ni = wv&1;
  float4v acc = (float4v){0.f,0.f,0.f,0.f};
  int vpx = tid>>3, vseg = tid&7;

  uint4 wpre = make_uint4(0,0,0,0);
  uint2 vpre = make_uint2(0,0);
  { // prefetch kc=0
    if(tid < 128) wpre = *(const uint4*)(Wob + tid*8);
    int idx = sIdx[vpx];
    if(idx >= 0) vpre = *(const uint2*)(xtb + idx + (vseg<<2));
  }
#pragma unroll 1
  for(int kc=0; kc<72; ++kc){
    if(tid < 128) *(uint4*)(&Ws[(tid>>2)*LSTR + (tid&3)*8]) = wpre;
    *(uint2*)(&Vs[vpx*LSTR + (vseg<<2)]) = vpre;
    __syncthreads();
    int kn = kc<71 ? kc+1 : kc;
    {
      if(tid < 128) wpre = *(const uint4*)(Wob + ((size_t)kn<<10) + tid*8);
      int tap = kn>>3, c0 = (kn&7)<<5;
      int idx = sIdx[(tap<<5) + vpx];
      vpre = make_uint2(0,0);
      if(idx >= 0) vpre = *(const uint2*)(xtb + idx + c0 + (vseg<<2));
    }
    short8 afr = *(const short8*)(&Ws[(mi*16+lo)*LSTR + hi*8]);
    short8 bfr = *(const short8*)(&Vs[(ni*16+lo)*LSTR + hi*8]);
    acc = __builtin_amdgcn_mfma_f32_16x16x32_bf16(afr, bfr, acc, 0,0,0);
    __syncthreads();
  }
  int p = px0 + ni*16 + lo;
  int ob = mi*16 + hi*4;
#pragma unroll
  for(int r=0;r<4;r++){
    int o = ob + r;
    if(o < 27) om[(size_t)(b*27+o)*HW + p] = acc[r];
  }
}

// ---------- DCN MFMA: Mb=256, Nb=32, K=2304, fused bilinear gather, reg-prefetch ----------
// grid (128,4) = 512 blocks (2/CU), 256 thr = 4 waves; wave wv: o in [wv*64,+64) x 32 px.
__global__ __launch_bounds__(256) void k_dcn_mfma(const ushort* __restrict__ xtb,
                        const float* __restrict__ om, const float* __restrict__ b_off,
                        const ushort* __restrict__ Wdb,
                        const float* __restrict__ b_dcn, float* __restrict__ out1){
  __shared__ ushort Ws[256*LSTR];     // 20480 B
  __shared__ ushort Vs[32*LSTR];      //  2560 B
  __shared__ int    sPk[288];
  __shared__ float4 sCf[288];
  int tid = threadIdx.x;
  int px0 = blockIdx.x * 32;
  int b   = blockIdx.y;

  for(int t=tid; t<288; t+=256){
    int k = t>>5, px = t&31;
    int p = px0 + px, hh = p>>6, ww = p&63;
    const float* omp = om + (size_t)b*27*HW + p;
    float dy = omp[(size_t)k*HW]      + b_off[k];
    float dx = omp[(size_t)(9+k)*HW]  + b_off[9+k];
    float mo = sigmoidf_(omp[(size_t)(18+k)*HW] + b_off[18+k]);
    float py  = dy + (float)(hh + k/3 - 1);
    float pxf = dx + (float)(ww + k%3 - 1);
    float y0 = floorf(py), x0 = floorf(pxf);
    float wy = py - y0, wx = pxf - x0;
    float y1 = y0 + 1.0f, x1 = x0 + 1.0f;
    bool vy0 = (y0>=0.f)&&(y0<=63.f), vy1 = (y1>=0.f)&&(y1<=63.f);
    bool vx0 = (x0>=0.f)&&(x0<=63.f), vx1 = (x1>=0.f)&&(x1<=63.f);
    int iy0 = (int)fminf(fmaxf(y0,0.f),63.f);
    int iy1 = (int)fminf(fmaxf(y1,0.f),63.f);
    int ix0 = (int)fminf(fmaxf(x0,0.f),63.f);
    int ix1 = (int)fminf(fmaxf(x1,0.f),63.f);
    sPk[t] = iy0 | (iy1<<6) | (ix0<<12) | (ix1<<18);
    sCf[t] = make_float4((vy0&&vx0)? (1.f-wy)*(1.f-wx)*mo : 0.f,
                         (vy0&&vx1)? (1.f-wy)*wx*mo       : 0.f,
                         (vy1&&vx0)? wy*(1.f-wx)*mo       : 0.f,
                         (vy1&&vx1)? wy*wx*mo             : 0.f);
  }
  __syncthreads();

  int lane = tid&63, wv = tid>>6, lo = lane&15, hi = lane>>4;
  float4v acc[4][2];
#pragma unroll
  for(int i=0;i<4;i++)
#pragma unroll
    for(int j=0;j<2;j++) acc[i][j] = (float4v){0.f,0.f,0.f,0.f};
  int cbase = (b*HW)<<8;
  int vpx = tid>>3, vseg = tid&7;

  uint4 wpre[4];
  uint2 cpre[4];
  { // prefetch kc=0
#pragma unroll
    for(int it=0;it<4;it++){ int g = tid + it*256; wpre[it] = *(const uint4*)(Wdb + g*8); }
    int pk = sPk[vpx];
    int coff = (vseg<<2);
    int iy0 = pk&63, iy1 = (pk>>6)&63, ix0 = (pk>>12)&63, ix1 = (pk>>18)&63;
    cpre[0] = *(const uint2*)(xtb + cbase + (((iy0<<6)+ix0)<<8) + coff);
    cpre[1] = *(const uint2*)(xtb + cbase + (((iy0<<6)+ix1)<<8) + coff);
    cpre[2] = *(const uint2*)(xtb + cbase + (((iy1<<6)+ix0)<<8) + coff);
    cpre[3] = *(const uint2*)(xtb + cbase + (((iy1<<6)+ix1)<<8) + coff);
  }
#pragma unroll 1
  for(int kc=0; kc<72; ++kc){
#pragma unroll
    for(int it=0;it<4;it++){ int g = tid + it*256; *(uint4*)(&Ws[(g>>2)*LSTR + (g&3)*8]) = wpre[it]; }
    {
      int k = kc>>3;
      float4 cf = sCf[(k<<5) + vpx];
      uint2 q00 = cpre[0], q01 = cpre[1], q10 = cpre[2], q11 = cpre[3];
      union{ ushort us[4]; uint2 q; } rr;
      rr.us[0] = f2bf(cf.x*bflo(q00.x)+cf.y*bflo(q01.x)+cf.z*bflo(q10.x)+cf.w*bflo(q11.x));
      rr.us[1] = f2bf(cf.x*bfhi(q00.x)+cf.y*bfhi(q01.x)+cf.z*bfhi(q10.x)+cf.w*bfhi(q11.x));
      rr.us[2] = f2bf(cf.x*bflo(q00.y)+cf.y*bflo(q01.y)+cf.z*bflo(q10.y)+cf.w*bflo(q11.y));
      rr.us[3] = f2bf(cf.x*bfhi(q00.y)+cf.y*bfhi(q01.y)+cf.z*bfhi(q10.y)+cf.w*bfhi(q11.y));
      *(uint2*)(&Vs[vpx*LSTR + (vseg<<2)]) = rr.q;
    }
    __syncthreads();
    int kn = kc<71 ? kc+1 : kc;
    { // prefetch kn
      const ushort* wp = Wdb + ((size_t)kn<<13);
#pragma unroll
      for(int it=0;it<4;it++){ int g = tid + it*256; wpre[it] = *(const uint4*)(wp + g*8); }
      int k = kn>>3, c0 = (kn&7)<<5;
      int pk = sPk[(k<<5) + vpx];
      int coff = c0 + (vseg<<2);
      int iy0 = pk&63, iy1 = (pk>>6)&63, ix0 = (pk>>12)&63, ix1 = (pk>>18)&63;
      cpre[0] = *(const uint2*)(xtb + cbase + (((iy0<<6)+ix0)<<8) + coff);
      cpre[1] = *(const uint2*)(xtb + cbase + (((iy0<<6)+ix1)<<8) + coff);
      cpre[2] = *(const uint2*)(xtb + cbase + (((iy1<<6)+ix0)<<8) + coff);
      cpre[3] = *(const uint2*)(xtb + cbase + (((iy1<<6)+ix1)<<8) + coff);
    }
    // compute
    const ushort* ap = &Ws[(wv*64 + lo)*LSTR + hi*8];
    const ushort* bp = &Vs[lo*LSTR + hi*8];
    short8 bfr[2];
#pragma unroll
    for(int j=0;j<2;j++) bfr[j] = *(const short8*)(bp + j*16*LSTR);
#pragma unroll
    for(int i=0;i<4;i++){
      short8 afr = *(const short8*)(ap + i*16*LSTR);
#pragma unroll
      for(int j=0;j<2;j++)
        acc[i][j] = __builtin_amdgcn_mfma_f32_16x16x32_bf16(afr, bfr[j], acc[i][j], 0,0,0);
    }
    __syncthreads();
  }

#pragma unroll
  for(int i=0;i<4;i++){
    int ob = wv*64 + i*16 + hi*4;
#pragma unroll
    for(int r=0;r<4;r++){
      int o = ob + r;
      float bias = b_dcn[o];
      float* op = out1 + (size_t)(b*COUT + o)*HW + px0 + lo;
#pragma unroll
      for(int j=0;j<2;j++) op[j*16] = acc[i][j][r] + bias;
    }
  }
}

// ---------- batchnorm stats (f32 input, for out1) ----------
__global__ void k_bn_stats(const float* __restrict__ xin, float* __restrict__ stats, int per_b){
  int o = blockIdx.x, tid = threadIdx.x;
  float s=0.f, ss=0.f;
  for(int b=0;b<B_;b++){
    const float* p = xin + (size_t)(b*COUT+o)*per_b;
    for(int i=tid;i<per_b;i+=256){ float v = p[i]; s+=v; ss+=v*v; }
  }
  __shared__ float rs[256], rss[256];
  rs[tid]=s; rss[tid]=ss; __syncthreads();
  for(int st=128; st>0; st>>=1){
    if(tid<st){ rs[tid]+=rs[tid+st]; rss[tid]+=rss[tid+st]; }
    __syncthreads();
  }
  if(tid==0){
    float n = (float)(B_*per_b);
    float mean = rs[0]/n;
    float var  = rss[0]/n - mean*mean;
    stats[o*2] = mean; stats[o*2+1] = rsqrtf(var + 1e-5f);
  }
}

// ---------- batchnorm stats over bf16 ct [16 planes][o][4096] ----------
__global__ void k_bn_stats_ct(const ushort* __restrict__ ct, float* __restrict__ stats){
  int o = blockIdx.x, tid = threadIdx.x;
  float s=0.f, ss=0.f;
  for(int pl=0; pl<16; ++pl){
    const ushort* p = ct + (((size_t)(pl*256 + o))<<12);
    for(int i=tid*8; i<4096; i+=2048){
      uint4 v = *(const uint4*)(p + i);
      float f;
      f=bflo(v.x); s+=f; ss+=f*f;  f=bfhi(v.x); s+=f; ss+=f*f;
      f=bflo(v.y); s+=f; ss+=f*f;  f=bfhi(v.y); s+=f; ss+=f*f;
      f=bflo(v.z); s+=f; ss+=f*f;  f=bfhi(v.z); s+=f; ss+=f*f;
      f=bflo(v.w); s+=f; ss+=f*f;  f=bfhi(v.w); s+=f; ss+=f*f;
    }
  }
  __shared__ float rs[256], rss[256];
  rs[tid]=s; rss[tid]=ss; __syncthreads();
  for(int st=128; st>0; st>>=1){
    if(tid<st){ rs[tid]+=rs[tid+st]; rss[tid]+=rss[tid+st]; }
    __syncthreads();
  }
  if(tid==0){
    float n = (float)(16*4096);
    float mean = rs[0]/n;
    float var  = rss[0]/n - mean*mean;
    stats[o*2] = mean; stats[o*2+1] = rsqrtf(var + 1e-5f);
  }
}

// ---------- BN1 apply + relu + transpose -> y1b bf16 [b][p][c] ----------
__global__ void k_bn1_apply_t(const float* __restrict__ out1, const float* __restrict__ stats,
                              const float* __restrict__ gamma, const float* __restrict__ beta,
                              ushort* __restrict__ y1b){
  __shared__ float ts[32][33];
  int tx = threadIdx.x & 31, ty = threadIdx.x >> 5;
  int p0 = blockIdx.x*32, o0 = blockIdx.y*32, b = blockIdx.z;
#pragma unroll
  for(int q=0;q<4;q++){
    int oo = ty + q*8; int o = o0 + oo;
    float m = stats[o*2], rstd = stats[o*2+1];
    float scale = rstd * gamma[o];
    float shift = beta[o] - m * scale;
    float v = out1[(size_t)(b*COUT+o)*HW + p0+tx];
    ts[oo][tx] = fmaxf(v*scale + shift, 0.f);
  }
  __syncthreads();
#pragma unroll
  for(int q=0;q<4;q++){
    int pr = ty + q*8;
    y1b[((size_t)(b*HW + p0+pr)<<8) + o0+tx] = f2bf(ts[tx][pr]);
  }
}

// ---------- conv-transpose MFMA: Mb=256 o, Nb=256 px, one (b,pp); reg-prefetch ----------
// grid (16,4,4) = 256 blocks, 512 thr = 8 waves; wave: o-quarter (wv>>1), px-half (wv&1).
// Output: ct[pp*4+b][o][px] bf16, contiguous (parity interleave deferred to BN2).
__global__ __launch_bounds__(512) void k_convt_mfma(const ushort* __restrict__ y1b,
                        const ushort* __restrict__ WT2c,
                        ushort* __restrict__ ct){
  __shared__ ushort Ws[256*LSTR];
  __shared__ ushort Vs[256*LSTR];
  __shared__ int sIdx[1024];
  int tid = threadIdx.x;
  int px0 = blockIdx.x * 256;
  int b   = blockIdx.y;
  int pp  = blockIdx.z;
  int ph = pp>>1, pw = pp&1;

  for(int t=tid; t<1024; t+=512){
    int ab = t>>8, px = t&255;
    int a = ab>>1, bb = ab&1;
    int p = px0+px, r = p>>6, s = p&63;
    int ih = r + ph - 1 + a, iw = s + pw - 1 + bb;
    sIdx[t] = (ih>=0 && ih<64 && iw>=0 && iw<64) ? ((b*HW + ih*64+iw)<<8) : -1;
  }
  __syncthreads();

  int lane = tid&63, wv = tid>>6, lo = lane&15, hi = lane>>4;
  int om0 = (wv>>1)*64;
  int pn0 = (wv&1)*128;
  float4v acc[4][8];
#pragma unroll
  for(int i=0;i<4;i++)
#pragma unroll
    for(int j=0;j<8;j++) acc[i][j] = (float4v){0.f,0.f,0.f,0.f};

  const ushort* wbase = WT2c + ((size_t)pp<<18);
  uint4 wpre[2], vpre[2];
  { // prefetch kc=0
    wpre[0] = *(const uint4*)(wbase + tid*8);
    wpre[1] = *(const uint4*)(wbase + (tid+512)*8);
    int idx = sIdx[tid>>1];
    int co = (tid&1)*16;
    vpre[0] = vpre[1] = make_uint4(0,0,0,0);
    if(idx >= 0){
      vpre[0] = *(const uint4*)(y1b + idx + co);
      vpre[1] = *(const uint4*)(y1b + idx + co + 8);
    }
  }
#pragma unroll 1
  for(int kc=0; kc<32; ++kc){
    {
      int g1 = tid + 512;
      *(uint4*)(&Ws[(tid>>2)*LSTR + (tid&3)*8]) = wpre[0];
      *(uint4*)(&Ws[(g1>>2)*LSTR + (g1&3)*8])   = wpre[1];
      int vpx = tid>>1, co = (tid&1)*16;
      *(uint4*)(&Vs[vpx*LSTR + co])     = vpre[0];
      *(uint4*)(&Vs[vpx*LSTR + co + 8]) = vpre[1];
    }
    __syncthreads();
    int kn = kc<31 ? kc+1 : kc;
    {
      const ushort* wp = wbase + (kn<<13);
      wpre[0] = *(const uint4*)(wp + tid*8);
      wpre[1] = *(const uint4*)(wp + (tid+512)*8);
      int ab = kn>>3, c0 = (kn&7)<<5;
      int idx = sIdx[(ab<<8) + (tid>>1)];
      int co = c0 + (tid&1)*16;
      vpre[0] = vpre[1] = make_uint4(0,0,0,0);
      if(idx >= 0){
        vpre[0] = *(const uint4*)(y1b + idx + co);
        vpre[1] = *(const uint4*)(y1b + idx + co + 8);
      }
    }
    const ushort* ap = &Ws[(om0 + lo)*LSTR + hi*8];
    const ushort* bp = &Vs[(pn0 + lo)*LSTR + hi*8];
    short8 bfr[8];
#pragma unroll
    for(int j=0;j<8;j++) bfr[j] = *(const short8*)(bp + j*16*LSTR);
#pragma unroll
    for(int i=0;i<4;i++){
      short8 afr = *(const short8*)(ap + i*16*LSTR);
#pragma unroll
      for(int j=0;j<8;j++)
        acc[i][j] = __builtin_amdgcn_mfma_f32_16x16x32_bf16(afr, bfr[j], acc[i][j], 0,0,0);
    }
    __syncthreads();
  }

  ushort* cb = ct + (((size_t)(pp*4 + b)*256)<<12);
#pragma unroll
  for(int i=0;i<4;i++){
#pragma unroll
    for(int r=0;r<4;r++){
      int o = om0 + i*16 + hi*4 + r;
      ushort* row = cb + ((size_t)o<<12) + px0 + pn0 + lo;
#pragma unroll
      for(int j=0;j<8;j++) row[j*16] = f2bf(acc[i][j][r]);
    }
  }
}

// ---------- BN2 apply + relu + parity interleave: ct bf16 -> out f32 ----------
__global__ void k_bn2_apply(const ushort* __restrict__ ct, const float* __restrict__ stats,
                            const float* __restrict__ gamma, const float* __restrict__ beta,
                            float* __restrict__ out){
  int gid = blockIdx.x*256 + threadIdx.x;   // grid 16384
  int e4 = gid<<2;
  int b = e4>>22, o = (e4>>14)&255, q = e4&16383;
  int H2 = q>>7, W2 = q&127;
  int r = H2>>1, ph = H2&1, s0 = W2>>1;
  size_t base0 = (((size_t)((ph*2)*4 + b)*256 + o)<<12) + r*64 + s0;
  unsigned u0 = *(const unsigned*)(ct + base0);
  unsigned u1 = *(const unsigned*)(ct + base0 + ((size_t)4<<20));
  float m = stats[o*2], rstd = stats[o*2+1];
  float sc = rstd * gamma[o];
  float sh = beta[o] - m * sc;
  float4 v;
  v.x = fmaxf(bflo(u0)*sc + sh, 0.f);
  v.y = fmaxf(bflo(u1)*sc + sh, 0.f);
  v.z = fmaxf(bfhi(u0)*sc + sh, 0.f);
  v.w = fmaxf(bfhi(u1)*sc + sh, 0.f);
  *(float4*)(out + e4) = v;
}

extern "C" void kernel_launch(void* const* d_in, const int* in_sizes, int n_in,
                              void* d_out, int out_size, void* d_ws, size_t ws_size,
                              hipStream_t stream){
  (void)in_sizes; (void)n_in; (void)out_size; (void)ws_size;
  const float* x     = (const float*)d_in[0];
  const float* w_off = (const float*)d_in[1];
  const float* b_off = (const float*)d_in[2];
  const float* w_dcn = (const float*)d_in[3];
  const float* b_dcn = (const float*)d_in[4];
  const float* gamma1= (const float*)d_in[5];
  const float* beta1 = (const float*)d_in[6];
  const float* w_up  = (const float*)d_in[7];
  const float* gamma2= (const float*)d_in[8];
  const float* beta2 = (const float*)d_in[9];
  float* out = (float*)d_out;

  // Workspace (floats). ct (bf16, 32 MB = 8388608 floats) aliases om+xtb+out1,
  // all of which are dead before k_convt_mfma runs.
  float* ws   = (float*)d_ws;
  ushort* ct  = (ushort*)ws;                       // [0, 8388608) floats
  float* om   = ws;                                // 442368 floats
  ushort* xtb = (ushort*)(ws + 442368);            // 4194304 bf16 = 2097152 floats
  float* out1 = ws + 442368 + 2097152;             // 4194304 floats, ends 6733824 < 8388608
  float* base2 = ws + 8388608;
  ushort* y1b  = (ushort*)base2;                                   // 4194304 bf16
  ushort* WT2c = (ushort*)(base2 + 2097152);                       // 1048576 bf16
  ushort* Wdb  = (ushort*)(base2 + 2097152 + 524288);              // 589824 bf16
  ushort* Wob  = (ushort*)(base2 + 2097152 + 524288 + 294912);     // 73728 bf16
  float* st1   = base2 + 2097152 + 524288 + 294912 + 36864;        // 512
  float* st2   = st1 + 512;                                        // 512

  k_transpose_x <<<dim3(128,8,4), 256, 0, stream>>>(x, xtb);
  k_build_Wob   <<<288,  256, 0, stream>>>(w_off, Wob);
  k_build_Wdb   <<<2304, 256, 0, stream>>>(w_dcn, Wdb);
  k_build_WT2c  <<<4096, 256, 0, stream>>>(w_up, WT2c);
  k_offset_mfma <<<dim3(128,4), 256, 0, stream>>>(xtb, Wob, om);
  k_dcn_mfma    <<<dim3(128,4), 256, 0, stream>>>(xtb, om, b_off, Wdb, b_dcn, out1);
  k_bn_stats    <<<256,  256, 0, stream>>>(out1, st1, 4096);
  k_bn1_apply_t <<<dim3(128,8,4), 256, 0, stream>>>(out1, st1, gamma1, beta1, y1b);
  k_convt_mfma  <<<dim3(16,4,4),  512, 0, stream>>>(y1b, WT2c, ct);
  k_bn_stats_ct <<<256,  256, 0, stream>>>(ct, st2);
  k_bn2_apply   <<<16384,256, 0, stream>>>(ct, st2, gamma2, beta2, out);
}

// Round 7
// 327.273 us; speedup vs baseline: 1.3561x; 1.3561x over previous
//
#include <hip/hip_runtime.h>
#include <hip/hip_bf16.h>
#include <math.h>

// Problem constants
#define B_   4
#define CIN  256
#define COUT 256
#define HW   4096   // 64*64

typedef __attribute__((ext_vector_type(8))) short short8;
typedef __attribute__((ext_vector_type(4))) float float4v;

// LDS row stride (ushorts). 80 B: 16B-aligned, period-8 bank pattern -> 2-way (free).
#define LSTR 40

__device__ __forceinline__ float sigmoidf_(float v){ return 1.0f/(1.0f+expf(-v)); }
__device__ __forceinline__ ushort f2bf(float f){
  union { float f; unsigned u; } x; x.f = f;
  unsigned r = x.u + 0x7fffu + ((x.u>>16)&1u);
  return (ushort)(r>>16);
}
__device__ __forceinline__ float bflo(unsigned u){ union{unsigned u; float f;} c; c.u = u<<16;          return c.f; }
__device__ __forceinline__ float bfhi(unsigned u){ union{unsigned u; float f;} c; c.u = u & 0xffff0000u; return c.f; }

// ---------- transpose x [B][C][HW] -> xtb [B][HW][C] bf16 ----------
__global__ void k_transpose_x(const float* __restrict__ x, ushort* __restrict__ xtb){
  __shared__ float ts[32][33];
  int tx = threadIdx.x & 31, ty = threadIdx.x >> 5;
  int p0 = blockIdx.x * 32, c0 = blockIdx.y * 32, b = blockIdx.z;
  const float* xb = x + (size_t)b*CIN*HW;
#pragma unroll
  for(int q=0;q<4;q++){
    int c = ty + q*8;
    ts[c][tx] = xb[(size_t)(c0+c)*HW + p0+tx];
  }
  __syncthreads();
#pragma unroll
  for(int q=0;q<4;q++){
    int pr = ty + q*8;
    xtb[((size_t)(b*HW + p0+pr)<<8) + c0+tx] = f2bf(ts[tx][pr]);
  }
}

// ---------- weight re-layouts (bf16, K-chunked [kc][o][kk]) ----------
__global__ void k_build_Wob(const float* __restrict__ w_off, ushort* __restrict__ Wob){
  int f = blockIdx.x*256 + threadIdx.x;   // grid 288
  int kc = f>>10, o = (f>>5)&31, kk = f&31;
  int k = kc*32 + kk, tap = k>>8, c = k&255;
  float v = (o < 27) ? w_off[(size_t)o*2304 + c*9 + tap] : 0.f;
  Wob[f] = f2bf(v);
}
__global__ void k_build_Wdb(const float* __restrict__ w_dcn, ushort* __restrict__ Wdb){
  int f = blockIdx.x*256 + threadIdx.x;  // grid 2304
  int kc = f>>13, o = (f>>5)&255, kk = f&31;
  int k = kc>>3, c = ((kc&7)<<5) | kk;
  Wdb[f] = f2bf(w_dcn[(size_t)o*2304 + c*9 + k]);
}
__global__ void k_build_WT2c(const float* __restrict__ w_up, ushort* __restrict__ WT2c){
  int f = blockIdx.x*256 + threadIdx.x;    // grid 4096
  int pp = f>>18, kc = (f>>13)&31, o = (f>>5)&255, kk = f&31;
  int k = kc*32 + kk, ab = k>>8, c = k&255;
  int a = ab>>1, bb = ab&1, ph = pp>>1, pw = pp&1;
  WT2c[f] = f2bf(w_up[(size_t)(c*COUT+o)*16 + (3-ph-2*a)*4 + (3-pw-2*bb)]);
}

// ---------- offset conv MFMA: M=32(27), Nb=64 px, K=2304, reg-prefetch (round-5 shape) ----------
// grid (64,4) = 256 blocks, 256 thr = 4 waves; wave wv owns px quarter, 2 m-tiles.
__global__ __launch_bounds__(256) void k_offset_mfma(const ushort* __restrict__ xtb,
                        const ushort* __restrict__ Wob, float* __restrict__ om){
  __shared__ ushort Ws[32*LSTR];
  __shared__ ushort Vs[64*LSTR];
  __shared__ int sIdx[576];
  int tid = threadIdx.x;
  int px0 = blockIdx.x * 64;
  int b   = blockIdx.y;
  for(int t=tid; t<576; t+=256){
    int tap = t>>6, px = t&63;
    int p = px0+px, hh = p>>6, ww = p&63;
    int ih = hh + tap/3 - 1, iw = ww + tap%3 - 1;
    sIdx[t] = (ih>=0 && ih<64 && iw>=0 && iw<64) ? ((b*HW + ih*64+iw)<<8) : -1;
  }
  __syncthreads();

  int lane = tid&63, wv = tid>>6, lo = lane&15, hi = lane>>4;
  float4v acc[2];
  acc[0] = acc[1] = (float4v){0.f,0.f,0.f,0.f};
  int vpx = tid>>2, vseg = tid&3;

  uint4 wpre = make_uint4(0,0,0,0), vpre = make_uint4(0,0,0,0);
  { // prefetch kc=0
    if(tid < 128) wpre = *(const uint4*)(Wob + tid*8);
    int idx = sIdx[vpx];
    if(idx >= 0) vpre = *(const uint4*)(xtb + idx + (vseg<<3));
  }
#pragma unroll 1
  for(int kc=0; kc<72; ++kc){
    if(tid < 128) *(uint4*)(&Ws[(tid>>2)*LSTR + (tid&3)*8]) = wpre;
    *(uint4*)(&Vs[vpx*LSTR + (vseg<<3)]) = vpre;
    __syncthreads();
    int kn = kc<71 ? kc+1 : kc;
    {
      if(tid < 128) wpre = *(const uint4*)(Wob + ((size_t)kn<<10) + tid*8);
      int tap = kn>>3, c0 = (kn&7)<<5;
      int idx = sIdx[(tap<<6) + vpx];
      vpre = make_uint4(0,0,0,0);
      if(idx >= 0) vpre = *(const uint4*)(xtb + idx + c0 + (vseg<<3));
    }
    short8 bfr = *(const short8*)(&Vs[(wv*16+lo)*LSTR + hi*8]);
#pragma unroll
    for(int mi=0;mi<2;mi++){
      short8 afr = *(const short8*)(&Ws[(mi*16+lo)*LSTR + hi*8]);
      acc[mi] = __builtin_amdgcn_mfma_f32_16x16x32_bf16(afr, bfr, acc[mi], 0,0,0);
    }
    __syncthreads();
  }
  int p = px0 + wv*16 + lo;
#pragma unroll
  for(int mi=0;mi<2;mi++){
    int ob = mi*16 + hi*4;
#pragma unroll
    for(int r=0;r<4;r++){
      int o = ob + r;
      if(o < 27) om[(size_t)(b*27+o)*HW + p] = acc[mi][r];
    }
  }
}

// ---------- DCN MFMA: Mb=256, Nb=64, K=2304, double-buffered LDS, 1 barrier/iter ----------
// grid (64,4) = 256 blocks, 512 thr = 8 waves (2/SIMD).
// Wave wv: o-strip (wv>>1)*64, px-half (wv&1)*32 -> 4x2 tiles = 8 MFMA/iter.
// b_dcn dropped: BN1 subtracts the per-channel mean, so a uniform bias cancels.
__global__ __launch_bounds__(512) void k_dcn_mfma(const ushort* __restrict__ xtb,
                        const float* __restrict__ om, const float* __restrict__ b_off,
                        const ushort* __restrict__ Wdb, float* __restrict__ out1){
  __shared__ ushort Ws[2][256*LSTR];   // 2 x 20480 B
  __shared__ ushort Vs[2][64*LSTR];    // 2 x  5120 B
  __shared__ int    sPk[576];
  __shared__ float4 sCf[576];
  int tid = threadIdx.x;
  int px0 = blockIdx.x * 64;
  int b   = blockIdx.y;

  for(int t=tid; t<576; t+=512){
    int k = t>>6, px = t&63;
    int p = px0 + px, hh = p>>6, ww = p&63;
    const float* omp = om + (size_t)b*27*HW + p;
    float dy = omp[(size_t)k*HW]      + b_off[k];
    float dx = omp[(size_t)(9+k)*HW]  + b_off[9+k];
    float mo = sigmoidf_(omp[(size_t)(18+k)*HW] + b_off[18+k]);
    float py  = dy + (float)(hh + k/3 - 1);
    float pxf = dx + (float)(ww + k%3 - 1);
    float y0 = floorf(py), x0 = floorf(pxf);
    float wy = py - y0, wx = pxf - x0;
    float y1 = y0 + 1.0f, x1 = x0 + 1.0f;
    bool vy0 = (y0>=0.f)&&(y0<=63.f), vy1 = (y1>=0.f)&&(y1<=63.f);
    bool vx0 = (x0>=0.f)&&(x0<=63.f), vx1 = (x1>=0.f)&&(x1<=63.f);
    int iy0 = (int)fminf(fmaxf(y0,0.f),63.f);
    int iy1 = (int)fminf(fmaxf(y1,0.f),63.f);
    int ix0 = (int)fminf(fmaxf(x0,0.f),63.f);
    int ix1 = (int)fminf(fmaxf(x1,0.f),63.f);
    sPk[t] = iy0 | (iy1<<6) | (ix0<<12) | (ix1<<18);
    sCf[t] = make_float4((vy0&&vx0)? (1.f-wy)*(1.f-wx)*mo : 0.f,
                         (vy0&&vx1)? (1.f-wy)*wx*mo       : 0.f,
                         (vy1&&vx0)? wy*(1.f-wx)*mo       : 0.f,
                         (vy1&&vx1)? wy*wx*mo             : 0.f);
  }
  __syncthreads();

  int lane = tid&63, wv = tid>>6, lo = lane&15, hi = lane>>4;
  int om0 = (wv>>1)*64, pn0 = (wv&1)*32;
  float4v acc[4][2];
#pragma unroll
  for(int i=0;i<4;i++)
#pragma unroll
    for(int j=0;j<2;j++) acc[i][j] = (float4v){0.f,0.f,0.f,0.f};
  int cbase = (b*HW)<<8;
  int vpx = tid>>3, vseg = tid&7;

  uint4 wpre[2];
  uint2 cpre[4];
  float4 cfp;

  // ---- prefetch chunk 0 ----
  {
    wpre[0] = *(const uint4*)(Wdb + tid*8);
    wpre[1] = *(const uint4*)(Wdb + (tid+512)*8);
    int pk = sPk[vpx]; cfp = sCf[vpx];
    int coff = (vseg<<2);
    int iy0 = pk&63, iy1 = (pk>>6)&63, ix0 = (pk>>12)&63, ix1 = (pk>>18)&63;
    cpre[0] = *(const uint2*)(xtb + cbase + (((iy0<<6)+ix0)<<8) + coff);
    cpre[1] = *(const uint2*)(xtb + cbase + (((iy0<<6)+ix1)<<8) + coff);
    cpre[2] = *(const uint2*)(xtb + cbase + (((iy1<<6)+ix0)<<8) + coff);
    cpre[3] = *(const uint2*)(xtb + cbase + (((iy1<<6)+ix1)<<8) + coff);
  }
  // ---- write chunk 0 -> buf 0 ----
  {
    int g1 = tid + 512;
    *(uint4*)(&Ws[0][(tid>>2)*LSTR + (tid&3)*8]) = wpre[0];
    *(uint4*)(&Ws[0][(g1>>2)*LSTR + (g1&3)*8])   = wpre[1];
    union{ ushort us[4]; uint2 q; } rr;
    rr.us[0] = f2bf(cfp.x*bflo(cpre[0].x)+cfp.y*bflo(cpre[1].x)+cfp.z*bflo(cpre[2].x)+cfp.w*bflo(cpre[3].x));
    rr.us[1] = f2bf(cfp.x*bfhi(cpre[0].x)+cfp.y*bfhi(cpre[1].x)+cfp.z*bfhi(cpre[2].x)+cfp.w*bfhi(cpre[3].x));
    rr.us[2] = f2bf(cfp.x*bflo(cpre[0].y)+cfp.y*bflo(cpre[1].y)+cfp.z*bflo(cpre[2].y)+cfp.w*bflo(cpre[3].y));
    rr.us[3] = f2bf(cfp.x*bfhi(cpre[0].y)+cfp.y*bfhi(cpre[1].y)+cfp.z*bfhi(cpre[2].y)+cfp.w*bfhi(cpre[3].y));
    *(uint2*)(&Vs[0][vpx*LSTR + (vseg<<2)]) = rr.q;
  }
  __syncthreads();

#pragma unroll 1
  for(int kc=0; kc<72; ++kc){
    int cur = kc&1;
    if(kc < 71){ // prefetch next chunk
      int kn = kc+1;
      const ushort* wp = Wdb + ((size_t)kn<<13);
      wpre[0] = *(const uint4*)(wp + tid*8);
      wpre[1] = *(const uint4*)(wp + (tid+512)*8);
      int k = kn>>3, c0 = (kn&7)<<5;
      int t = (k<<6) + vpx;
      int pk = sPk[t]; cfp = sCf[t];
      int coff = c0 + (vseg<<2);
      int iy0 = pk&63, iy1 = (pk>>6)&63, ix0 = (pk>>12)&63, ix1 = (pk>>18)&63;
      cpre[0] = *(const uint2*)(xtb + cbase + (((iy0<<6)+ix0)<<8) + coff);
      cpre[1] = *(const uint2*)(xtb + cbase + (((iy0<<6)+ix1)<<8) + coff);
      cpre[2] = *(const uint2*)(xtb + cbase + (((iy1<<6)+ix0)<<8) + coff);
      cpre[3] = *(const uint2*)(xtb + cbase + (((iy1<<6)+ix1)<<8) + coff);
    }
    // compute on buf[cur]
    const ushort* ap = &Ws[cur][(om0 + lo)*LSTR + hi*8];
    const ushort* bp = &Vs[cur][(pn0 + lo)*LSTR + hi*8];
    short8 bfr[2];
#pragma unroll
    for(int j=0;j<2;j++) bfr[j] = *(const short8*)(bp + j*16*LSTR);
#pragma unroll
    for(int i=0;i<4;i++){
      short8 afr = *(const short8*)(ap + i*16*LSTR);
#pragma unroll
      for(int j=0;j<2;j++)
        acc[i][j] = __builtin_amdgcn_mfma_f32_16x16x32_bf16(afr, bfr[j], acc[i][j], 0,0,0);
    }
    if(kc < 71){ // write prefetched -> buf[cur^1]
      int nxt = cur^1;
      int g1 = tid + 512;
      *(uint4*)(&Ws[nxt][(tid>>2)*LSTR + (tid&3)*8]) = wpre[0];
      *(uint4*)(&Ws[nxt][(g1>>2)*LSTR + (g1&3)*8])   = wpre[1];
      union{ ushort us[4]; uint2 q; } rr;
      rr.us[0] = f2bf(cfp.x*bflo(cpre[0].x)+cfp.y*bflo(cpre[1].x)+cfp.z*bflo(cpre[2].x)+cfp.w*bflo(cpre[3].x));
      rr.us[1] = f2bf(cfp.x*bfhi(cpre[0].x)+cfp.y*bfhi(cpre[1].x)+cfp.z*bfhi(cpre[2].x)+cfp.w*bfhi(cpre[3].x));
      rr.us[2] = f2bf(cfp.x*bflo(cpre[0].y)+cfp.y*bflo(cpre[1].y)+cfp.z*bflo(cpre[2].y)+cfp.w*bflo(cpre[3].y));
      rr.us[3] = f2bf(cfp.x*bfhi(cpre[0].y)+cfp.y*bfhi(cpre[1].y)+cfp.z*bfhi(cpre[2].y)+cfp.w*bfhi(cpre[3].y));
      *(uint2*)(&Vs[nxt][vpx*LSTR + (vseg<<2)]) = rr.q;
    }
    __syncthreads();
  }

#pragma unroll
  for(int i=0;i<4;i++){
    int ob = om0 + i*16 + hi*4;
#pragma unroll
    for(int r=0;r<4;r++){
      int o = ob + r;
      float* op = out1 + (size_t)(b*COUT + o)*HW + px0 + pn0 + lo;
#pragma unroll
      for(int j=0;j<2;j++) op[j*16] = acc[i][j][r];
    }
  }
}

// ---------- batchnorm stats (f32 input, for out1) ----------
__global__ void k_bn_stats(const float* __restrict__ xin, float* __restrict__ stats, int per_b){
  int o = blockIdx.x, tid = threadIdx.x;
  float s=0.f, ss=0.f;
  for(int b=0;b<B_;b++){
    const float* p = xin + (size_t)(b*COUT+o)*per_b;
    for(int i=tid;i<per_b;i+=256){ float v = p[i]; s+=v; ss+=v*v; }
  }
  __shared__ float rs[256], rss[256];
  rs[tid]=s; rss[tid]=ss; __syncthreads();
  for(int st=128; st>0; st>>=1){
    if(tid<st){ rs[tid]+=rs[tid+st]; rss[tid]+=rss[tid+st]; }
    __syncthreads();
  }
  if(tid==0){
    float n = (float)(B_*per_b);
    float mean = rs[0]/n;
    float var  = rss[0]/n - mean*mean;
    stats[o*2] = mean; stats[o*2+1] = rsqrtf(var + 1e-5f);
  }
}

// ---------- batchnorm stats over bf16 ct [16 planes][o][4096] ----------
__global__ void k_bn_stats_ct(const ushort* __restrict__ ct, float* __restrict__ stats){
  int o = blockIdx.x, tid = threadIdx.x;
  float s=0.f, ss=0.f;
  for(int pl=0; pl<16; ++pl){
    const ushort* p = ct + (((size_t)(pl*256 + o))<<12);
    for(int i=tid*8; i<4096; i+=2048){
      uint4 v = *(const uint4*)(p + i);
      float f;
      f=bflo(v.x); s+=f; ss+=f*f;  f=bfhi(v.x); s+=f; ss+=f*f;
      f=bflo(v.y); s+=f; ss+=f*f;  f=bfhi(v.y); s+=f; ss+=f*f;
      f=bflo(v.z); s+=f; ss+=f*f;  f=bfhi(v.z); s+=f; ss+=f*f;
      f=bflo(v.w); s+=f; ss+=f*f;  f=bfhi(v.w); s+=f; ss+=f*f;
    }
  }
  __shared__ float rs[256], rss[256];
  rs[tid]=s; rss[tid]=ss; __syncthreads();
  for(int st=128; st>0; st>>=1){
    if(tid<st){ rs[tid]+=rs[tid+st]; rss[tid]+=rss[tid+st]; }
    __syncthreads();
  }
  if(tid==0){
    float n = (float)(16*4096);
    float mean = rs[0]/n;
    float var  = rss[0]/n - mean*mean;
    stats[o*2] = mean; stats[o*2+1] = rsqrtf(var + 1e-5f);
  }
}

// ---------- BN1 apply + relu + transpose -> y1b bf16 [b][p][c] ----------
__global__ void k_bn1_apply_t(const float* __restrict__ out1, const float* __restrict__ stats,
                              const float* __restrict__ gamma, const float* __restrict__ beta,
                              ushort* __restrict__ y1b){
  __shared__ float ts[32][33];
  int tx = threadIdx.x & 31, ty = threadIdx.x >> 5;
  int p0 = blockIdx.x*32, o0 = blockIdx.y*32, b = blockIdx.z;
#pragma unroll
  for(int q=0;q<4;q++){
    int oo = ty + q*8; int o = o0 + oo;
    float m = stats[o*2], rstd = stats[o*2+1];
    float scale = rstd * gamma[o];
    float shift = beta[o] - m * scale;
    float v = out1[(size_t)(b*COUT+o)*HW + p0+tx];
    ts[oo][tx] = fmaxf(v*scale + shift, 0.f);
  }
  __syncthreads();
#pragma unroll
  for(int q=0;q<4;q++){
    int pr = ty + q*8;
    y1b[((size_t)(b*HW + p0+pr)<<8) + o0+tx] = f2bf(ts[tx][pr]);
  }
}

// ---------- conv-transpose MFMA: Mb=256 o, Nb=256 px, one (b,pp); reg-prefetch ----------
__global__ __launch_bounds__(512) void k_convt_mfma(const ushort* __restrict__ y1b,
                        const ushort* __restrict__ WT2c,
                        ushort* __restrict__ ct){
  __shared__ ushort Ws[256*LSTR];
  __shared__ ushort Vs[256*LSTR];
  __shared__ int sIdx[1024];
  int tid = threadIdx.x;
  int px0 = blockIdx.x * 256;
  int b   = blockIdx.y;
  int pp  = blockIdx.z;
  int ph = pp>>1, pw = pp&1;

  for(int t=tid; t<1024; t+=512){
    int ab = t>>8, px = t&255;
    int a = ab>>1, bb = ab&1;
    int p = px0+px, r = p>>6, s = p&63;
    int ih = r + ph - 1 + a, iw = s + pw - 1 + bb;
    sIdx[t] = (ih>=0 && ih<64 && iw>=0 && iw<64) ? ((b*HW + ih*64+iw)<<8) : -1;
  }
  __syncthreads();

  int lane = tid&63, wv = tid>>6, lo = lane&15, hi = lane>>4;
  int om0 = (wv>>1)*64;
  int pn0 = (wv&1)*128;
  float4v acc[4][8];
#pragma unroll
  for(int i=0;i<4;i++)
#pragma unroll
    for(int j=0;j<8;j++) acc[i][j] = (float4v){0.f,0.f,0.f,0.f};

  const ushort* wbase = WT2c + ((size_t)pp<<18);
  uint4 wpre[2], vpre[2];
  { // prefetch kc=0
    wpre[0] = *(const uint4*)(wbase + tid*8);
    wpre[1] = *(const uint4*)(wbase + (tid+512)*8);
    int idx = sIdx[tid>>1];
    int co = (tid&1)*16;
    vpre[0] = vpre[1] = make_uint4(0,0,0,0);
    if(idx >= 0){
      vpre[0] = *(const uint4*)(y1b + idx + co);
      vpre[1] = *(const uint4*)(y1b + idx + co + 8);
    }
  }
#pragma unroll 1
  for(int kc=0; kc<32; ++kc){
    {
      int g1 = tid + 512;
      *(uint4*)(&Ws[(tid>>2)*LSTR + (tid&3)*8]) = wpre[0];
      *(uint4*)(&Ws[(g1>>2)*LSTR + (g1&3)*8])   = wpre[1];
      int vpx = tid>>1, co = (tid&1)*16;
      *(uint4*)(&Vs[vpx*LSTR + co])     = vpre[0];
      *(uint4*)(&Vs[vpx*LSTR + co + 8]) = vpre[1];
    }
    __syncthreads();
    int kn = kc<31 ? kc+1 : kc;
    {
      const ushort* wp = wbase + (kn<<13);
      wpre[0] = *(const uint4*)(wp + tid*8);
      wpre[1] = *(const uint4*)(wp + (tid+512)*8);
      int ab = kn>>3, c0 = (kn&7)<<5;
      int idx = sIdx[(ab<<8) + (tid>>1)];
      int co = c0 + (tid&1)*16;
      vpre[0] = vpre[1] = make_uint4(0,0,0,0);
      if(idx >= 0){
        vpre[0] = *(const uint4*)(y1b + idx + co);
        vpre[1] = *(const uint4*)(y1b + idx + co + 8);
      }
    }
    const ushort* ap = &Ws[(om0 + lo)*LSTR + hi*8];
    const ushort* bp = &Vs[(pn0 + lo)*LSTR + hi*8];
    short8 bfr[8];
#pragma unroll
    for(int j=0;j<8;j++) bfr[j] = *(const short8*)(bp + j*16*LSTR);
#pragma unroll
    for(int i=0;i<4;i++){
      short8 afr = *(const short8*)(ap + i*16*LSTR);
#pragma unroll
      for(int j=0;j<8;j++)
        acc[i][j] = __builtin_amdgcn_mfma_f32_16x16x32_bf16(afr, bfr[j], acc[i][j], 0,0,0);
    }
    __syncthreads();
  }

  ushort* cb = ct + (((size_t)(pp*4 + b)*256)<<12);
#pragma unroll
  for(int i=0;i<4;i++){
#pragma unroll
    for(int r=0;r<4;r++){
      int o = om0 + i*16 + hi*4 + r;
      ushort* row = cb + ((size_t)o<<12) + px0 + pn0 + lo;
#pragma unroll
      for(int j=0;j<8;j++) row[j*16] = f2bf(acc[i][j][r]);
    }
  }
}

// ---------- BN2 apply + relu + parity interleave: ct bf16 -> out f32 ----------
__global__ void k_bn2_apply(const ushort* __restrict__ ct, const float* __restrict__ stats,
                            const float* __restrict__ gamma, const float* __restrict__ beta,
                            float* __restrict__ out){
  int gid = blockIdx.x*256 + threadIdx.x;   // grid 16384
  int e4 = gid<<2;
  int b = e4>>22, o = (e4>>14)&255, q = e4&16383;
  int H2 = q>>7, W2 = q&127;
  int r = H2>>1, ph = H2&1, s0 = W2>>1;
  size_t base0 = (((size_t)((ph*2)*4 + b)*256 + o)<<12) + r*64 + s0;
  unsigned u0 = *(const unsigned*)(ct + base0);
  unsigned u1 = *(const unsigned*)(ct + base0 + ((size_t)4<<20));
  float m = stats[o*2], rstd = stats[o*2+1];
  float sc = rstd * gamma[o];
  float sh = beta[o] - m * sc;
  float4 v;
  v.x = fmaxf(bflo(u0)*sc + sh, 0.f);
  v.y = fmaxf(bflo(u1)*sc + sh, 0.f);
  v.z = fmaxf(bfhi(u0)*sc + sh, 0.f);
  v.w = fmaxf(bfhi(u1)*sc + sh, 0.f);
  *(float4*)(out + e4) = v;
}

extern "C" void kernel_launch(void* const* d_in, const int* in_sizes, int n_in,
                              void* d_out, int out_size, void* d_ws, size_t ws_size,
                              hipStream_t stream){
  (void)in_sizes; (void)n_in; (void)out_size; (void)ws_size;
  const float* x     = (const float*)d_in[0];
  const float* w_off = (const float*)d_in[1];
  const float* b_off = (const float*)d_in[2];
  const float* w_dcn = (const float*)d_in[3];
  const float* gamma1= (const float*)d_in[5];
  const float* beta1 = (const float*)d_in[6];
  const float* w_up  = (const float*)d_in[7];
  const float* gamma2= (const float*)d_in[8];
  const float* beta2 = (const float*)d_in[9];
  float* out = (float*)d_out;

  // Workspace (floats). ct (bf16, 32 MB = 8388608 floats) aliases om+xtb+out1,
  // all of which are dead before k_convt_mfma runs.
  float* ws   = (float*)d_ws;
  ushort* ct  = (ushort*)ws;                       // [0, 8388608) floats
  float* om   = ws;                                // 442368 floats
  ushort* xtb = (ushort*)(ws + 442368);            // 4194304 bf16 = 2097152 floats
  float* out1 = ws + 442368 + 2097152;             // 4194304 floats, ends 6733824 < 8388608
  float* base2 = ws + 8388608;
  ushort* y1b  = (ushort*)base2;                                   // 4194304 bf16
  ushort* WT2c = (ushort*)(base2 + 2097152);                       // 1048576 bf16
  ushort* Wdb  = (ushort*)(base2 + 2097152 + 524288);              // 589824 bf16
  ushort* Wob  = (ushort*)(base2 + 2097152 + 524288 + 294912);     // 73728 bf16
  float* st1   = base2 + 2097152 + 524288 + 294912 + 36864;        // 512
  float* st2   = st1 + 512;                                        // 512

  k_transpose_x <<<dim3(128,8,4), 256, 0, stream>>>(x, xtb);
  k_build_Wob   <<<288,  256, 0, stream>>>(w_off, Wob);
  k_build_Wdb   <<<2304, 256, 0, stream>>>(w_dcn, Wdb);
  k_build_WT2c  <<<4096, 256, 0, stream>>>(w_up, WT2c);
  k_offset_mfma <<<dim3(64,4),  256, 0, stream>>>(xtb, Wob, om);
  k_dcn_mfma    <<<dim3(64,4),  512, 0, stream>>>(xtb, om, b_off, Wdb, out1);
  k_bn_stats    <<<256,  256, 0, stream>>>(out1, st1, 4096);
  k_bn1_apply_t <<<dim3(128,8,4), 256, 0, stream>>>(out1, st1, gamma1, beta1, y1b);
  k_convt_mfma  <<<dim3(16,4,4),  512, 0, stream>>>(y1b, WT2c, ct);
  k_bn_stats_ct <<<256,  256, 0, stream>>>(ct, st2);
  k_bn2_apply   <<<16384,256, 0, stream>>>(ct, st2, gamma2, beta2, out);
}